// Round 1
// baseline (418.513 us; speedup 1.0000x reference)
//
#include <hip/hip_runtime.h>

// IndRNN (recurrent-only): h_t = relu(x_t + w_hh * h_{t-1})
// x: [T=2048, B=64, H=512] fp32, weight_hh: [H] fp32, out: [T, B, H] fp32.
// One thread per (b,h) chain: 32768 threads, each scans T sequentially.
// Loads of x are independent of the recurrence -> deep double-buffered
// prefetch (DEPTH=32 per buffer) hides HBM latency despite the serial FMA.

#define HIDDEN 512
#define SEQ 2048
#define BATCH 64

constexpr int NCHAIN = BATCH * HIDDEN;   // 32768 independent chains
constexpr int STRIDE = BATCH * HIDDEN;   // element stride between t and t+1
constexpr int DEPTH = 32;                // prefetch depth per buffer

template <bool PF>
__device__ __forceinline__ void run_chunk(float& hv, const float wh,
                                          const float (&cur)[DEPTH],
                                          float (&nxt)[DEPTH],
                                          const float* __restrict__ xn,
                                          float* __restrict__ o) {
#pragma unroll
  for (int i = 0; i < DEPTH; ++i) {
    if (PF) nxt[i] = __builtin_nontemporal_load(xn + (long)i * STRIDE);
    hv = fmaxf(0.0f, fmaf(wh, hv, cur[i]));
    __builtin_nontemporal_store(hv, o + (long)i * STRIDE);
  }
}

__global__ __launch_bounds__(64) void indrnn_kernel(
    const float* __restrict__ x, const float* __restrict__ w,
    float* __restrict__ out) {
  const int idx = blockIdx.x * 64 + threadIdx.x;  // b*H + h
  const float wh = w[idx & (HIDDEN - 1)];
  const float* xp = x + idx;
  float* op = out + idx;

  float bufA[DEPTH], bufB[DEPTH];
#pragma unroll
  for (int i = 0; i < DEPTH; ++i)
    bufA[i] = __builtin_nontemporal_load(xp + (long)i * STRIDE);

  float hv = 0.0f;
  int t = 0;
#pragma unroll 1
  for (; t + 2 * DEPTH < SEQ; t += 2 * DEPTH) {
    run_chunk<true>(hv, wh, bufA, bufB, xp + (long)(t + DEPTH) * STRIDE,
                    op + (long)t * STRIDE);
    run_chunk<true>(hv, wh, bufB, bufA, xp + (long)(t + 2 * DEPTH) * STRIDE,
                    op + (long)(t + DEPTH) * STRIDE);
  }
  // Tail pair: first half still prefetches the final chunk, second half none.
  run_chunk<true>(hv, wh, bufA, bufB, xp + (long)(t + DEPTH) * STRIDE,
                  op + (long)t * STRIDE);
  run_chunk<false>(hv, wh, bufB, bufA, nullptr,
                   op + (long)(t + DEPTH) * STRIDE);
}

extern "C" void kernel_launch(void* const* d_in, const int* in_sizes, int n_in,
                              void* d_out, int out_size, void* d_ws,
                              size_t ws_size, hipStream_t stream) {
  const float* x = (const float*)d_in[0];
  const float* w = (const float*)d_in[1];
  float* out = (float*)d_out;
  indrnn_kernel<<<NCHAIN / 64, 64, 0, stream>>>(x, w, out);
}